// Round 3
// baseline (669.913 us; speedup 1.0000x reference)
//
#include <hip/hip_runtime.h>
#include <hip/hip_bf16.h>
#include <math.h>

typedef __hip_bfloat16 bf16;
static __device__ __forceinline__ float b2f(bf16 v) { return __bfloat162float(v); }

constexpr int NN = 200000;   // nodes
constexpr int NE = 600000;   // edges
constexpr int NG = 512;      // graphs

// ---------------- degree / counts ----------------
__global__ void k_deg(const int* __restrict__ dst, float* __restrict__ deg) {
    int e = blockIdx.x * blockDim.x + threadIdx.x;
    if (e < NE) atomicAdd(&deg[dst[e]], 1.0f);
}

__global__ void k_counts(const int* __restrict__ batch, float* __restrict__ counts) {
    int n = blockIdx.x * blockDim.x + threadIdx.x;
    if (n < NN) atomicAdd(&counts[batch[n]], 1.0f);
}

__global__ void k_dis(float* __restrict__ deg) {
    int n = blockIdx.x * blockDim.x + threadIdx.x;
    if (n < NN) deg[n] = rsqrtf(deg[n] + 1.0f);   // +1 self-loop
}

// ---------------- edge scatter of raw x (2 channels): xa[d] += x[s]*w ----------------
__global__ void k_edgex(const int* __restrict__ ei, const float* __restrict__ dis,
                        const float* __restrict__ x, float* __restrict__ xa) {
    int e = blockIdx.x * blockDim.x + threadIdx.x;
    if (e >= NE) return;
    int s = ei[e], d = ei[NE + e];
    float w = dis[s] * dis[d];
    atomicAdd(&xa[d * 2 + 0], x[s * 2 + 0] * w);
    atomicAdd(&xa[d * 2 + 1], x[s * 2 + 1] * w);
}

// ---------------- h1 = relu((xa + x*dis^2) @ W1 + b1) -> bf16 ----------------
__global__ void k_h1(const float* __restrict__ x, const float* __restrict__ xa,
                     const float* __restrict__ dis, const float* __restrict__ W1,
                     const float* __restrict__ b1, bf16* __restrict__ h1) {
    int t = blockIdx.x * blockDim.x + threadIdx.x;
    if (t >= NN * 64) return;
    int n = t >> 6, k = t & 63;
    float dd = dis[n]; dd *= dd;
    float a0 = xa[n * 2 + 0] + x[n * 2 + 0] * dd;
    float a1 = xa[n * 2 + 1] + x[n * 2 + 1] * dd;
    float v = a0 * W1[k] + a1 * W1[64 + k] + b1[k];
    h1[t] = __float2bfloat16(fmaxf(v, 0.0f));
}

// ---------------- edge scatter of h1 (64 channels): agg[d] += h1[s]*w ----------------
__global__ void k_edgeh(const int* __restrict__ ei, const float* __restrict__ dis,
                        const bf16* __restrict__ h1, float* __restrict__ agg) {
    int t = blockIdx.x * blockDim.x + threadIdx.x;
    if (t >= NE * 64) return;
    int e = t >> 6, k = t & 63;
    int s = ei[e], d = ei[NE + e];
    float w = dis[s] * dis[d];
    atomicAdd(&agg[d * 64 + k], b2f(h1[s * 64 + k]) * w);
}

// ---------------- fused: g=(agg + h1*dis^2); h2=relu(g@W2+b2); pool atomically ----------------
constexpr int BNODE = 16;
__global__ void k_l2pool(const float* __restrict__ agg, const bf16* __restrict__ h1,
                         const float* __restrict__ dis, const float* __restrict__ W2,
                         const float* __restrict__ b2, const int* __restrict__ batch,
                         float* __restrict__ pooled) {
    __shared__ float gs[BNODE][64];
    __shared__ float w2s[64 * 128];
    __shared__ int bsh[BNODE];
    int n0 = blockIdx.x * BNODE;
    int tid = threadIdx.x;

    // stage W2 into LDS
    for (int i = tid; i < 64 * 128; i += 256)
        w2s[i] = W2[i];
    // stage g rows
    for (int i = tid; i < BNODE * 64; i += 256) {
        int nl = i >> 6, j = i & 63;
        int n = n0 + nl;
        if (n < NN) {
            float dd = dis[n]; dd *= dd;
            gs[nl][j] = agg[n * 64 + j] + b2f(h1[n * 64 + j]) * dd;
        } else gs[nl][j] = 0.0f;
    }
    if (tid < BNODE) {
        int n = n0 + tid;
        bsh[tid] = (n < NN) ? batch[n] : 0;
    }
    __syncthreads();

    int col = tid & 127;
    int half = tid >> 7;
    float bias = b2[col];
    for (int nl = half; nl < BNODE; nl += 2) {
        int n = n0 + nl;
        if (n >= NN) break;
        float acc = bias;
#pragma unroll
        for (int j = 0; j < 64; j++) acc += gs[nl][j] * w2s[j * 128 + col];
        acc = fmaxf(acc, 0.0f);
        atomicAdd(&pooled[bsh[nl] * 128 + col], acc);
    }
}

// ---------------- fused head: feat MLP + fusion MLP + sigmoid, block per graph ----------------
__global__ void k_head(const float* __restrict__ feat,
                       const float* __restrict__ fW1, const float* __restrict__ fb1,
                       const float* __restrict__ fg1, const float* __restrict__ fbe1,
                       const float* __restrict__ frm1, const float* __restrict__ frv1,
                       const float* __restrict__ fW2, const float* __restrict__ fb2,
                       const float* __restrict__ uW1, const float* __restrict__ ub1,
                       const float* __restrict__ ug1, const float* __restrict__ ube1,
                       const float* __restrict__ urm1, const float* __restrict__ urv1,
                       const float* __restrict__ uW2, const float* __restrict__ ub2,
                       const float* __restrict__ ug2, const float* __restrict__ ube2,
                       const float* __restrict__ urm2, const float* __restrict__ urv2,
                       const float* __restrict__ uW3, const float* __restrict__ ub3,
                       const float* __restrict__ pooled, const float* __restrict__ counts,
                       float* __restrict__ out) {
    int g = blockIdx.x;
    int tid = threadIdx.x;
    __shared__ float t1[256], c[256], d1[192], d2[128];

    float f[8];
#pragma unroll
    for (int i = 0; i < 8; i++) f[i] = feat[g * 8 + i];

    // feat MLP layer 1: 8 -> 256, BN, ReLU
    {
        int j = tid;
        float acc = fb1[j];
#pragma unroll
        for (int i = 0; i < 8; i++) acc += f[i] * fW1[i * 256 + j];
        acc = (acc - frm1[j]) * rsqrtf(frv1[j] + 1e-5f) * fg1[j] + fbe1[j];
        t1[j] = fmaxf(acc, 0.0f);
    }
    __syncthreads();

    // feat MLP layer 2 (256->128) into c[128..255]; pooled mean into c[0..127]
    if (tid < 128) {
        float acc = fb2[tid];
        for (int j = 0; j < 256; j++) acc += t1[j] * fW2[j * 128 + tid];
        c[128 + tid] = acc;
    } else {
        int k = tid - 128;
        float cnt = fmaxf(counts[g], 1.0f);
        c[k] = pooled[g * 128 + k] / cnt;
    }
    __syncthreads();

    // fusion layer 1: 256 -> 192, BN, ReLU
    if (tid < 192) {
        float acc = ub1[tid];
        for (int i = 0; i < 256; i++) acc += c[i] * uW1[i * 192 + tid];
        acc = (acc - urm1[tid]) * rsqrtf(urv1[tid] + 1e-5f) * ug1[tid] + ube1[tid];
        d1[tid] = fmaxf(acc, 0.0f);
    }
    __syncthreads();

    // fusion layer 2: 192 -> 128, BN, ReLU
    if (tid < 128) {
        float acc = ub2[tid];
        for (int i = 0; i < 192; i++) acc += d1[i] * uW2[i * 128 + tid];
        acc = (acc - urm2[tid]) * rsqrtf(urv2[tid] + 1e-5f) * ug2[tid] + ube2[tid];
        d2[tid] = fmaxf(acc, 0.0f);
    }
    __syncthreads();

    // fusion layer 3: 128 -> 1, sigmoid
    if (tid == 0) {
        float s = ub3[0];
        for (int i = 0; i < 128; i++) s += d2[i] * uW3[i];
        out[g] = 1.0f / (1.0f + expf(-s));
    }
}

extern "C" void kernel_launch(void* const* d_in, const int* in_sizes, int n_in,
                              void* d_out, int out_size, void* d_ws, size_t ws_size,
                              hipStream_t stream) {
    const float* x    = (const float*)d_in[0];
    const float* feat = (const float*)d_in[1];
    const float* W1   = (const float*)d_in[2];
    const float* b1   = (const float*)d_in[3];
    const float* W2   = (const float*)d_in[4];
    const float* b2   = (const float*)d_in[5];
    const float* fW1  = (const float*)d_in[6];
    const float* fb1  = (const float*)d_in[7];
    const float* fg1  = (const float*)d_in[8];
    const float* fbe1 = (const float*)d_in[9];
    const float* frm1 = (const float*)d_in[10];
    const float* frv1 = (const float*)d_in[11];
    const float* fW2  = (const float*)d_in[12];
    const float* fb2  = (const float*)d_in[13];
    const float* uW1  = (const float*)d_in[14];
    const float* ub1  = (const float*)d_in[15];
    const float* ug1  = (const float*)d_in[16];
    const float* ube1 = (const float*)d_in[17];
    const float* urm1 = (const float*)d_in[18];
    const float* urv1 = (const float*)d_in[19];
    const float* uW2  = (const float*)d_in[20];
    const float* ub2  = (const float*)d_in[21];
    const float* ug2  = (const float*)d_in[22];
    const float* ube2 = (const float*)d_in[23];
    const float* urm2 = (const float*)d_in[24];
    const float* urv2 = (const float*)d_in[25];
    const float* uW3  = (const float*)d_in[26];
    const float* ub3  = (const float*)d_in[27];
    const int* ei    = (const int*)d_in[28];   // [2, E]
    const int* batch = (const int*)d_in[29];   // [N]
    float* out = (float*)d_out;

    // workspace layout — total ~80 MB
    char* p = (char*)d_ws;
    float* dis    = (float*)p; p += (size_t)NN * 4;            // deg -> dis in place
    float* xa     = (float*)p; p += (size_t)NN * 2 * 4;        // aggregated x
    float* agg    = (float*)p; p += (size_t)NN * 64 * 4;       // aggregated h1
    bf16*  h1     = (bf16*)p;  p += (size_t)NN * 64 * 2;       // relu'd layer-1 output
    float* counts = (float*)p; p += (size_t)NG * 4;
    float* pooled = (float*)p; p += (size_t)NG * 128 * 4;

    hipMemsetAsync(dis,    0, (size_t)NN * 4, stream);
    hipMemsetAsync(xa,     0, (size_t)NN * 2 * 4, stream);
    hipMemsetAsync(agg,    0, (size_t)NN * 64 * 4, stream);
    hipMemsetAsync(counts, 0, (size_t)NG * 4, stream);
    hipMemsetAsync(pooled, 0, (size_t)NG * 128 * 4, stream);

    k_deg<<<(NE + 255) / 256, 256, 0, stream>>>(ei + NE, dis);
    k_counts<<<(NN + 255) / 256, 256, 0, stream>>>(batch, counts);
    k_dis<<<(NN + 255) / 256, 256, 0, stream>>>(dis);

    // GCN layer 1: aggregate x first (2 channels), then W1+bias+relu
    k_edgex<<<(NE + 255) / 256, 256, 0, stream>>>(ei, dis, x, xa);
    k_h1<<<(NN * 64 + 255) / 256, 256, 0, stream>>>(x, xa, dis, W1, b1, h1);

    // GCN layer 2: aggregate h1 (64 channels), then fused W2+bias+relu+pool
    k_edgeh<<<(NE * 64 + 255) / 256, 256, 0, stream>>>(ei, dis, h1, agg);
    k_l2pool<<<(NN + BNODE - 1) / BNODE, 256, 0, stream>>>(agg, h1, dis, W2, b2, batch, pooled);

    // fused MLP head
    k_head<<<NG, 256, 0, stream>>>(feat, fW1, fb1, fg1, fbe1, frm1, frv1, fW2, fb2,
                                   uW1, ub1, ug1, ube1, urm1, urv1,
                                   uW2, ub2, ug2, ube2, urm2, urv2, uW3, ub3,
                                   pooled, counts, out);
}

// Round 4
// 473.484 us; speedup vs baseline: 1.4149x; 1.4149x over previous
//
#include <hip/hip_runtime.h>
#include <hip/hip_bf16.h>
#include <math.h>

typedef __hip_bfloat16 bf16;
static __device__ __forceinline__ float b2f(bf16 v) { return __bfloat162float(v); }

constexpr int NN = 200000;   // nodes
constexpr int NE = 600000;   // edges
constexpr int NG = 512;      // graphs

// ---------------- degree ----------------
__global__ void k_deg(const int* __restrict__ dst, float* __restrict__ deg) {
    int e = blockIdx.x * blockDim.x + threadIdx.x;
    if (e < NE) atomicAdd(&deg[dst[e]], 1.0f);
}

// counts[g] = #nodes with batch==g, via binary search on the SORTED batch array.
// (replaces the 207us atomic-contention k_counts: sorted batch made every wave
//  hammer one address)
__global__ void k_countsb(const int* __restrict__ batch, float* __restrict__ counts) {
    int g = blockIdx.x * blockDim.x + threadIdx.x;
    if (g >= NG) return;
    // lower_bound(g)
    int lo = 0, hi = NN;
    while (lo < hi) { int m = (lo + hi) >> 1; if (batch[m] < g) lo = m + 1; else hi = m; }
    int first = lo;
    // lower_bound(g+1)
    lo = 0; hi = NN;
    while (lo < hi) { int m = (lo + hi) >> 1; if (batch[m] < g + 1) lo = m + 1; else hi = m; }
    counts[g] = (float)(lo - first);
}

__global__ void k_dis(float* __restrict__ deg) {
    int n = blockIdx.x * blockDim.x + threadIdx.x;
    if (n < NN) deg[n] = rsqrtf(deg[n] + 1.0f);   // +1 self-loop
}

// ---------------- edge scatter of raw x (2 channels): xa[d] += x[s]*w ----------------
__global__ void k_edgex(const int* __restrict__ ei, const float* __restrict__ dis,
                        const float* __restrict__ x, float* __restrict__ xa) {
    int e = blockIdx.x * blockDim.x + threadIdx.x;
    if (e >= NE) return;
    int s = ei[e], d = ei[NE + e];
    float w = dis[s] * dis[d];
    atomicAdd(&xa[d * 2 + 0], x[s * 2 + 0] * w);
    atomicAdd(&xa[d * 2 + 1], x[s * 2 + 1] * w);
}

// ---------------- h1 = relu((xa + x*dis^2) @ W1 + b1) -> bf16 ----------------
__global__ void k_h1(const float* __restrict__ x, const float* __restrict__ xa,
                     const float* __restrict__ dis, const float* __restrict__ W1,
                     const float* __restrict__ b1, bf16* __restrict__ h1) {
    int t = blockIdx.x * blockDim.x + threadIdx.x;
    if (t >= NN * 64) return;
    int n = t >> 6, k = t & 63;
    float dd = dis[n]; dd *= dd;
    float a0 = xa[n * 2 + 0] + x[n * 2 + 0] * dd;
    float a1 = xa[n * 2 + 1] + x[n * 2 + 1] * dd;
    float v = a0 * W1[k] + a1 * W1[64 + k] + b1[k];
    h1[t] = __float2bfloat16(fmaxf(v, 0.0f));
}

// ---------------- edge scatter of h1 (64 channels): agg[d] += h1[s]*w ----------------
__global__ void k_edgeh(const int* __restrict__ ei, const float* __restrict__ dis,
                        const bf16* __restrict__ h1, float* __restrict__ agg) {
    int t = blockIdx.x * blockDim.x + threadIdx.x;
    if (t >= NE * 64) return;
    int e = t >> 6, k = t & 63;
    int s = ei[e], d = ei[NE + e];
    float w = dis[s] * dis[d];
    atomicAdd(&agg[d * 64 + k], b2f(h1[s * 64 + k]) * w);
}

// ---------------- fused: g=(agg + h1*dis^2); h2=relu(g@W2+b2); pool atomically ----------------
constexpr int BNODE = 16;
__global__ void k_l2pool(const float* __restrict__ agg, const bf16* __restrict__ h1,
                         const float* __restrict__ dis, const float* __restrict__ W2,
                         const float* __restrict__ b2, const int* __restrict__ batch,
                         float* __restrict__ pooled) {
    __shared__ float gs[BNODE][64];
    __shared__ float w2s[64 * 128];
    __shared__ int bsh[BNODE];
    int n0 = blockIdx.x * BNODE;
    int tid = threadIdx.x;

    // stage W2 into LDS
    for (int i = tid; i < 64 * 128; i += 256)
        w2s[i] = W2[i];
    // stage g rows
    for (int i = tid; i < BNODE * 64; i += 256) {
        int nl = i >> 6, j = i & 63;
        int n = n0 + nl;
        if (n < NN) {
            float dd = dis[n]; dd *= dd;
            gs[nl][j] = agg[n * 64 + j] + b2f(h1[n * 64 + j]) * dd;
        } else gs[nl][j] = 0.0f;
    }
    if (tid < BNODE) {
        int n = n0 + tid;
        bsh[tid] = (n < NN) ? batch[n] : 0;
    }
    __syncthreads();

    int col = tid & 127;
    int half = tid >> 7;
    float bias = b2[col];
    for (int nl = half; nl < BNODE; nl += 2) {
        int n = n0 + nl;
        if (n >= NN) break;
        float acc = bias;
#pragma unroll
        for (int j = 0; j < 64; j++) acc += gs[nl][j] * w2s[j * 128 + col];
        acc = fmaxf(acc, 0.0f);
        atomicAdd(&pooled[bsh[nl] * 128 + col], acc);
    }
}

// ---------------- fused head: feat MLP + fusion MLP + sigmoid, block per graph ----------------
__global__ void k_head(const float* __restrict__ feat,
                       const float* __restrict__ fW1, const float* __restrict__ fb1,
                       const float* __restrict__ fg1, const float* __restrict__ fbe1,
                       const float* __restrict__ frm1, const float* __restrict__ frv1,
                       const float* __restrict__ fW2, const float* __restrict__ fb2,
                       const float* __restrict__ uW1, const float* __restrict__ ub1,
                       const float* __restrict__ ug1, const float* __restrict__ ube1,
                       const float* __restrict__ urm1, const float* __restrict__ urv1,
                       const float* __restrict__ uW2, const float* __restrict__ ub2,
                       const float* __restrict__ ug2, const float* __restrict__ ube2,
                       const float* __restrict__ urm2, const float* __restrict__ urv2,
                       const float* __restrict__ uW3, const float* __restrict__ ub3,
                       const float* __restrict__ pooled, const float* __restrict__ counts,
                       float* __restrict__ out) {
    int g = blockIdx.x;
    int tid = threadIdx.x;
    __shared__ float t1[256], c[256], d1[192], d2[128];

    float f[8];
#pragma unroll
    for (int i = 0; i < 8; i++) f[i] = feat[g * 8 + i];

    // feat MLP layer 1: 8 -> 256, BN, ReLU
    {
        int j = tid;
        float acc = fb1[j];
#pragma unroll
        for (int i = 0; i < 8; i++) acc += f[i] * fW1[i * 256 + j];
        acc = (acc - frm1[j]) * rsqrtf(frv1[j] + 1e-5f) * fg1[j] + fbe1[j];
        t1[j] = fmaxf(acc, 0.0f);
    }
    __syncthreads();

    // feat MLP layer 2 (256->128) into c[128..255]; pooled mean into c[0..127]
    if (tid < 128) {
        float acc = fb2[tid];
        for (int j = 0; j < 256; j++) acc += t1[j] * fW2[j * 128 + tid];
        c[128 + tid] = acc;
    } else {
        int k = tid - 128;
        float cnt = fmaxf(counts[g], 1.0f);
        c[k] = pooled[g * 128 + k] / cnt;
    }
    __syncthreads();

    // fusion layer 1: 256 -> 192, BN, ReLU
    if (tid < 192) {
        float acc = ub1[tid];
        for (int i = 0; i < 256; i++) acc += c[i] * uW1[i * 192 + tid];
        acc = (acc - urm1[tid]) * rsqrtf(urv1[tid] + 1e-5f) * ug1[tid] + ube1[tid];
        d1[tid] = fmaxf(acc, 0.0f);
    }
    __syncthreads();

    // fusion layer 2: 192 -> 128, BN, ReLU
    if (tid < 128) {
        float acc = ub2[tid];
        for (int i = 0; i < 192; i++) acc += d1[i] * uW2[i * 128 + tid];
        acc = (acc - urm2[tid]) * rsqrtf(urv2[tid] + 1e-5f) * ug2[tid] + ube2[tid];
        d2[tid] = fmaxf(acc, 0.0f);
    }
    __syncthreads();

    // fusion layer 3: 128 -> 1, sigmoid
    if (tid == 0) {
        float s = ub3[0];
        for (int i = 0; i < 128; i++) s += d2[i] * uW3[i];
        out[g] = 1.0f / (1.0f + expf(-s));
    }
}

extern "C" void kernel_launch(void* const* d_in, const int* in_sizes, int n_in,
                              void* d_out, int out_size, void* d_ws, size_t ws_size,
                              hipStream_t stream) {
    const float* x    = (const float*)d_in[0];
    const float* feat = (const float*)d_in[1];
    const float* W1   = (const float*)d_in[2];
    const float* b1   = (const float*)d_in[3];
    const float* W2   = (const float*)d_in[4];
    const float* b2   = (const float*)d_in[5];
    const float* fW1  = (const float*)d_in[6];
    const float* fb1  = (const float*)d_in[7];
    const float* fg1  = (const float*)d_in[8];
    const float* fbe1 = (const float*)d_in[9];
    const float* frm1 = (const float*)d_in[10];
    const float* frv1 = (const float*)d_in[11];
    const float* fW2  = (const float*)d_in[12];
    const float* fb2  = (const float*)d_in[13];
    const float* uW1  = (const float*)d_in[14];
    const float* ub1  = (const float*)d_in[15];
    const float* ug1  = (const float*)d_in[16];
    const float* ube1 = (const float*)d_in[17];
    const float* urm1 = (const float*)d_in[18];
    const float* urv1 = (const float*)d_in[19];
    const float* uW2  = (const float*)d_in[20];
    const float* ub2  = (const float*)d_in[21];
    const float* ug2  = (const float*)d_in[22];
    const float* ube2 = (const float*)d_in[23];
    const float* urm2 = (const float*)d_in[24];
    const float* urv2 = (const float*)d_in[25];
    const float* uW3  = (const float*)d_in[26];
    const float* ub3  = (const float*)d_in[27];
    const int* ei    = (const int*)d_in[28];   // [2, E]
    const int* batch = (const int*)d_in[29];   // [N]
    float* out = (float*)d_out;

    // workspace layout — total ~80 MB
    char* p = (char*)d_ws;
    float* dis    = (float*)p; p += (size_t)NN * 4;            // deg -> dis in place
    float* xa     = (float*)p; p += (size_t)NN * 2 * 4;        // aggregated x
    float* agg    = (float*)p; p += (size_t)NN * 64 * 4;       // aggregated h1
    bf16*  h1     = (bf16*)p;  p += (size_t)NN * 64 * 2;       // relu'd layer-1 output
    float* counts = (float*)p; p += (size_t)NG * 4;
    float* pooled = (float*)p; p += (size_t)NG * 128 * 4;

    hipMemsetAsync(dis,    0, (size_t)NN * 4, stream);
    hipMemsetAsync(xa,     0, (size_t)NN * 2 * 4, stream);
    hipMemsetAsync(agg,    0, (size_t)NN * 64 * 4, stream);
    hipMemsetAsync(pooled, 0, (size_t)NG * 128 * 4, stream);

    k_deg<<<(NE + 255) / 256, 256, 0, stream>>>(ei + NE, dis);
    k_countsb<<<(NG + 255) / 256, 256, 0, stream>>>(batch, counts);
    k_dis<<<(NN + 255) / 256, 256, 0, stream>>>(dis);

    // GCN layer 1: aggregate x first (2 channels), then W1+bias+relu
    k_edgex<<<(NE + 255) / 256, 256, 0, stream>>>(ei, dis, x, xa);
    k_h1<<<(NN * 64 + 255) / 256, 256, 0, stream>>>(x, xa, dis, W1, b1, h1);

    // GCN layer 2: aggregate h1 (64 channels), then fused W2+bias+relu+pool
    k_edgeh<<<(NE * 64 + 255) / 256, 256, 0, stream>>>(ei, dis, h1, agg);
    k_l2pool<<<(NN + BNODE - 1) / BNODE, 256, 0, stream>>>(agg, h1, dis, W2, b2, batch, pooled);

    // fused MLP head
    k_head<<<NG, 256, 0, stream>>>(feat, fW1, fb1, fg1, fbe1, frm1, frv1, fW2, fb2,
                                   uW1, ub1, ug1, ube1, urm1, urv1,
                                   uW2, ub2, ug2, ube2, urm2, urv2, uW3, ub3,
                                   pooled, counts, out);
}